// Round 9
// baseline (220.374 us; speedup 1.0000x reference)
//
#include <hip/hip_runtime.h>
#include <hip/hip_bf16.h>
#include <stdint.h>
#include <math.h>

#define NROWS 16384
#define DHALF 384
#define DFULL 768
#define ROWB  384      // bytes per fp4 row: 768 elems * 4 bit
#define EPSF  1e-8f
#define QSCALE 64.0f   // N(0,0.036)*64 -> N(0,2.3): centered in e2m1 range +-6

typedef __attribute__((ext_vector_type(4)))  float f32x4;
typedef __attribute__((ext_vector_type(16))) float f32x16;
typedef __attribute__((ext_vector_type(4)))  int   int4v;
typedef __attribute__((ext_vector_type(8)))  int   int8v;

// ---- async global->LDS, 16B per lane (wave-uniform base + lane*16) ----
__device__ __forceinline__ void async_copy16(const void* gptr, void* lptr) {
    __builtin_amdgcn_global_load_lds(
        (const __attribute__((address_space(1))) unsigned int*)gptr,
        (__attribute__((address_space(3))) unsigned int*)lptr,
        16, 0, 0);
}

// monotone float->u32 (order-preserving for all finite floats)
__device__ __forceinline__ unsigned mono_u32(float v) {
    unsigned u = __float_as_uint(v);
    return u ^ ((unsigned)(((int)u) >> 31) | 0x80000000u);
}

// max with a DPP row_ror'd copy (16-lane row, pure VALU — no LDS traffic)
template <int CTRL>
__device__ __forceinline__ unsigned row_max_step(unsigned v) {
    unsigned t = (unsigned)__builtin_amdgcn_update_dpp(
        0, (int)v, CTRL, 0xF, 0xF, false);
    return v > t ? v : t;
}

// fp4 e2m1 encode, round-to-nearest: values {0,.5,1,1.5,2,3,4,6} (+sign)
__device__ __forceinline__ unsigned enc_fp4(float v) {
    float a = fabsf(v);
    unsigned c = (unsigned)(a >= 0.25f) + (a >= 0.75f) + (a >= 1.25f) +
                 (a >= 1.75f) + (a >= 2.5f) + (a >= 3.5f) + (a >= 5.0f);
    return c | (v < 0.0f ? 8u : 0u);
}

// pad 4-dword fp4 operand to the v8i32 the builtin wants (HW reads v[0:3])
__device__ __forceinline__ int8v to8(int4v q) {
    int8v r;
    r[0] = q[0]; r[1] = q[1]; r[2] = q[2]; r[3] = q[3];
    r[4] = 0; r[5] = 0; r[6] = 0; r[7] = 0;
    return r;
}

// ---------------------------------------------------------------------
// Kernel 1: per-row L2 norm over concat(a,b); write fp4-e2m1 nibbles of
// (x_norm * 64), pair-packed. Zeroes best[row].
// ---------------------------------------------------------------------
__global__ __launch_bounds__(256) void normalize_kernel(
    const float* __restrict__ a, const float* __restrict__ b,
    unsigned char* __restrict__ xq, float* __restrict__ invn,
    unsigned long long* __restrict__ best) {
    int wave = threadIdx.x >> 6;
    int lane = threadIdx.x & 63;
    int row  = blockIdx.x * 4 + wave;

    const float2* pa = (const float2*)(a + (size_t)row * DHALF);  // 192 pairs
    const float2* pb = (const float2*)(b + (size_t)row * DHALF);

    float2 va[3], vb[3];
    float s = 0.0f;
#pragma unroll
    for (int it = 0; it < 3; ++it) {
        va[it] = pa[lane + 64 * it];
        s += va[it].x * va[it].x + va[it].y * va[it].y;
    }
#pragma unroll
    for (int it = 0; it < 3; ++it) {
        vb[it] = pb[lane + 64 * it];
        s += vb[it].x * vb[it].x + vb[it].y * vb[it].y;
    }
#pragma unroll
    for (int d = 1; d < 64; d <<= 1) s += __shfl_xor(s, d, 64);

    float inv = 1.0f / fmaxf(sqrtf(s), EPSF);
    if (lane == 0) { invn[row] = inv; best[row] = 0ull; }
    float qs = inv * QSCALE;

    unsigned char* px = xq + (size_t)row * ROWB;
#pragma unroll
    for (int it = 0; it < 3; ++it)
        px[lane + 64 * it] =
            (unsigned char)(enc_fp4(va[it].x * qs) | (enc_fp4(va[it].y * qs) << 4));
#pragma unroll
    for (int it = 0; it < 3; ++it)
        px[192 + lane + 64 * it] =
            (unsigned char)(enc_fp4(vb[it].x * qs) | (enc_fp4(vb[it].y * qs) << 4));
}

// ---------------------------------------------------------------------
// Kernel 2: scaled dots via MX-fp4 32x32x64 MFMA (fmt 4), 128x128 tile,
// BK=128 elems = 64 B/row, upper-triangle blocks (symmetry). Each wave:
// 64x64 as 2x2 tiles of 32x32 — 8 MFMA + 8 operand builds per K-step
// (R8 ledger: VALUBusy 50% was the top pipe, dominated by 20 to8()
// tuple builds + 16 MFMA issues per K-step of the 16x16x128 shape).
// C/D layout (verified m74/m101, dtype-indep m127/m128):
//   col = lane&31, row = (reg&3) + 8*(reg>>2) + 4*(lane>>5).
// A/B granule: lane&31 = row, lane>>5 = 32-elem k-granule (analogy to
// 16x16x128's lane>>4, verified end-to-end in R7; shared k-permutation
// cancels in X·X^T). Dbuf LDS (R8, neutral-but-harmless), rolled K-loop
// (R4 lesson), 2-way-max swizzle (R7), packed-key epilogue (R6).
// ---------------------------------------------------------------------
__global__ __launch_bounds__(256, 3) void argmax_kernel(
    const unsigned char* __restrict__ xq,
    unsigned long long* __restrict__ best) {
    __shared__ unsigned char As[2][128 * 64];
    __shared__ unsigned char Bs[2][128 * 64];

    // decode upper-triangle pair: k -> (rb <= cb)
    int k = blockIdx.x;
    int i = (int)((sqrtf(8.0f * (float)k + 1.0f) - 1.0f) * 0.5f);
    while ((i + 1) * (i + 2) / 2 <= k) ++i;
    while (i * (i + 1) / 2 > k) --i;
    int cb = i;
    int rb = k - i * (i + 1) / 2;   // rb <= cb
    int r0 = rb * 128, c0 = cb * 128;

    int tid  = threadIdx.x;
    int wave = tid >> 6, lane = tid & 63;
    int wr = wave >> 1, wc = wave & 1;
    int l31 = lane & 31, half = lane >> 5;

    f32x16 acc[2][2] = {};
    const int SC = 0x7f7f7f7f;      // e8m0 scales = 1.0 in every byte

    // staging pointers: 2 rounds x 256 threads cover 512 granules/tile
    const unsigned char* gA[2];
    const unsigned char* gB[2];
    int lofs[2];
#pragma unroll
    for (int r2 = 0; r2 < 2; ++r2) {
        int idx = r2 * 256 + tid;          // 0..511
        int r   = idx >> 2;                // 0..127
        int s   = idx & 3;                 // dst slot
        int g   = s ^ ((r ^ (r >> 2)) & 3);   // swizzled source granule
        gA[r2] = xq + (size_t)(r0 + r) * ROWB + (g << 4);
        gB[r2] = xq + (size_t)(c0 + r) * ROWB + (g << 4);
        lofs[r2] = idx * 16;
    }

    auto stage = [&](int k0b, int buf) {
        async_copy16(gA[0] + k0b, &As[buf][lofs[0]]);
        async_copy16(gA[1] + k0b, &As[buf][lofs[1]]);
        async_copy16(gB[0] + k0b, &Bs[buf][lofs[0]]);
        async_copy16(gB[1] + k0b, &Bs[buf][lofs[1]]);
    };

    // fragment loader: local row rr in [0,128), granule gg in [0,4)
    auto ldfrag = [&](const unsigned char* base, int rr, int gg) -> int8v {
        int slot = gg ^ ((rr ^ (rr >> 2)) & 3);
        return to8(*(const int4v*)(base + rr * 64 + (slot << 4)));
    };

    int ra0 = wr * 64 + l31, ra1 = ra0 + 32;
    int rb0 = wc * 64 + l31, rb1 = rb0 + 32;

    auto compute = [&](int buf) {
        const unsigned char* Ab = As[buf];
        const unsigned char* Bb = Bs[buf];
#pragma unroll
        for (int ks = 0; ks < 2; ++ks) {
            int gg = 2 * ks + half;
            int8v a0 = ldfrag(Ab, ra0, gg);
            int8v a1 = ldfrag(Ab, ra1, gg);
            int8v b0 = ldfrag(Bb, rb0, gg);
            int8v b1 = ldfrag(Bb, rb1, gg);
            acc[0][0] = __builtin_amdgcn_mfma_scale_f32_32x32x64_f8f6f4(
                a0, b0, acc[0][0], 4, 4, 0, SC, 0, SC);
            acc[0][1] = __builtin_amdgcn_mfma_scale_f32_32x32x64_f8f6f4(
                a0, b1, acc[0][1], 4, 4, 0, SC, 0, SC);
            acc[1][0] = __builtin_amdgcn_mfma_scale_f32_32x32x64_f8f6f4(
                a1, b0, acc[1][0], 4, 4, 0, SC, 0, SC);
            acc[1][1] = __builtin_amdgcn_mfma_scale_f32_32x32x64_f8f6f4(
                a1, b1, acc[1][1], 4, 4, 0, SC, 0, SC);
        }
    };

    stage(0, 0);
    __syncthreads();
    int buf = 0;
#pragma unroll 1
    for (int k0b = 64; k0b < ROWB; k0b += 64) {   // 5 pipelined steps
        stage(k0b, buf ^ 1);
        compute(buf);
        __syncthreads();
        buf ^= 1;
    }
    compute(buf);                // last tile; epilogue is register-only

    int rbase = r0 + wr * 64, cbase = c0 + wc * 64;
    int h4 = half * 4;

    // Row-direction: per (ti, reg) this lane holds row
    //   rbase + ti*32 + (reg&3) + 8*(reg>>2) + 4*half, cols = tj*32 + l31.
    // Packed key low 6 bits = col-in-64. Reduce across the 32 lanes of
    // this half: 4x DPP row_ror (within 16) + shfl_xor 16.
#pragma unroll
    for (int ti = 0; ti < 2; ++ti) {
#pragma unroll
        for (int reg = 0; reg < 16; ++reg) {
            int grow = rbase + ti * 32 + (reg & 3) + 8 * (reg >> 2) + h4;
            unsigned bk = 0;
#pragma unroll
            for (int tj = 0; tj < 2; ++tj) {
                float v   = acc[ti][tj][reg];
                int  gcol = cbase + tj * 32 + l31;
                if (gcol == grow) v = -1.0e30f;   // diagonal mask
                unsigned u = (mono_u32(v) & ~63u) | (unsigned)(tj * 32 + l31);
                bk = bk > u ? bk : u;
            }
            bk = row_max_step<0x121>(bk);   // ror 1
            bk = row_max_step<0x122>(bk);   // ror 2
            bk = row_max_step<0x124>(bk);   // ror 4
            bk = row_max_step<0x128>(bk);   // ror 8
            unsigned t16 = (unsigned)__shfl_xor((int)bk, 16, 64);
            bk = bk > t16 ? bk : t16;
            if (l31 == 0) {
                int col = cbase + (int)(bk & 63u);
                unsigned long long gk =
                    ((unsigned long long)(bk & ~63u) << 32) | (unsigned)col;
                atomicMax(&best[grow], gk);
            }
        }
    }

    // Column-direction (off-diagonal blocks): fold (ti,reg) as row-in-64
    // into the key, then reduce the two halves via shfl_xor 32.
    if (rb != cb) {
#pragma unroll
        for (int tj = 0; tj < 2; ++tj) {
            unsigned bk = 0;
#pragma unroll
            for (int ti = 0; ti < 2; ++ti)
#pragma unroll
                for (int reg = 0; reg < 16; ++reg) {
                    int row64 = ti * 32 + (reg & 3) + 8 * (reg >> 2) + h4;
                    unsigned u = (mono_u32(acc[ti][tj][reg]) & ~63u) |
                                 (unsigned)row64;
                    bk = bk > u ? bk : u;
                }
            unsigned t32 = (unsigned)__shfl_xor((int)bk, 32, 64);
            bk = bk > t32 ? bk : t32;
            if (half == 0) {
                int grow = rbase + (int)(bk & 63u);
                int gcol = cbase + tj * 32 + l31;
                unsigned long long gk =
                    ((unsigned long long)(bk & ~63u) << 32) | (unsigned)grow;
                atomicMax(&best[gcol], gk);
            }
        }
    }
}

// ---------------------------------------------------------------------
// Kernel 3: per-row term = log(||xn_i - xn_j + eps|| + eps), fp32 from
// original inputs (float2 loads). One wave per row, coalesced store.
// ---------------------------------------------------------------------
__global__ __launch_bounds__(256) void loss_kernel(
    const float* __restrict__ a, const float* __restrict__ b,
    const float* __restrict__ invn,
    const unsigned long long* __restrict__ best,
    float* __restrict__ terms) {
    int wave = threadIdx.x >> 6;
    int lane = threadIdx.x & 63;
    int row  = blockIdx.x * 4 + wave;

    int j = (int)(best[row] & 0xffffffffull);
    float ii = invn[row], ij = invn[j];

    const float2* pai = (const float2*)(a + (size_t)row * DHALF);
    const float2* pbi = (const float2*)(b + (size_t)row * DHALF);
    const float2* paj = (const float2*)(a + (size_t)j * DHALF);
    const float2* pbj = (const float2*)(b + (size_t)j * DHALF);

    float s = 0.0f;
#pragma unroll
    for (int it = 0; it < 3; ++it) {
        int kk = lane + 64 * it;
        float2 di = pai[kk], dj = paj[kk];
        float dx = di.x * ii - dj.x * ij + EPSF;
        float dy = di.y * ii - dj.y * ij + EPSF;
        s += dx * dx + dy * dy;
    }
#pragma unroll
    for (int it = 0; it < 3; ++it) {
        int kk = lane + 64 * it;
        float2 di = pbi[kk], dj = pbj[kk];
        float dx = di.x * ii - dj.x * ij + EPSF;
        float dy = di.y * ii - dj.y * ij + EPSF;
        s += dx * dx + dy * dy;
    }
#pragma unroll
    for (int d = 1; d < 64; d <<= 1) s += __shfl_xor(s, d, 64);

    if (lane == 0) terms[row] = logf(sqrtf(s) + EPSF);
}

// ---------------------------------------------------------------------
// Kernel 4: single-block tree reduction of terms -> out[0] = -mean
// ---------------------------------------------------------------------
__global__ __launch_bounds__(1024) void reduce_kernel(
    const float* __restrict__ terms, float* __restrict__ out) {
    __shared__ float partial[16];
    int tid = threadIdx.x;
    float s = 0.0f;
#pragma unroll
    for (int it = 0; it < NROWS / 1024; ++it) s += terms[tid + 1024 * it];
#pragma unroll
    for (int d = 1; d < 64; d <<= 1) s += __shfl_xor(s, d, 64);
    if ((tid & 63) == 0) partial[tid >> 6] = s;
    __syncthreads();
    if (tid < 16) {
        s = partial[tid];
#pragma unroll
        for (int d = 1; d < 16; d <<= 1) s += __shfl_xor(s, d, 16);
        if (tid == 0) out[0] = -s * (1.0f / (float)NROWS);
    }
}

// ---------------------------------------------------------------------
extern "C" void kernel_launch(void* const* d_in, const int* in_sizes, int n_in,
                              void* d_out, int out_size, void* d_ws, size_t ws_size,
                              hipStream_t stream) {
    const float* a = (const float*)d_in[0];
    const float* b = (const float*)d_in[1];
    float* out = (float*)d_out;

    char* ws = (char*)d_ws;
    unsigned char* xq = (unsigned char*)ws;                                    // 6291456 B
    unsigned long long* best = (unsigned long long*)(ws + 6291456);            // 131072 B
    float* invn  = (float*)(ws + 6291456 + 131072);                            // 65536 B
    float* terms = (float*)(ws + 6291456 + 131072 + 65536);                    // 65536 B

    const int NTILE = NROWS / 128;                     // 128
    const int NBLK  = NTILE * (NTILE + 1) / 2;         // 8256

    normalize_kernel<<<NROWS / 4, 256, 0, stream>>>(a, b, xq, invn, best);
    argmax_kernel<<<NBLK, 256, 0, stream>>>(xq, best);
    loss_kernel<<<NROWS / 4, 256, 0, stream>>>(a, b, invn, best, terms);
    reduce_kernel<<<1, 1024, 0, stream>>>(terms, out);
}

// Round 10
// 207.566 us; speedup vs baseline: 1.0617x; 1.0617x over previous
//
#include <hip/hip_runtime.h>
#include <hip/hip_bf16.h>
#include <stdint.h>
#include <math.h>

#define NROWS 16384
#define DHALF 384
#define DFULL 768
#define ROWB  384      // bytes per fp4 row: 768 elems * 4 bit
#define EPSF  1e-8f
#define QSCALE 64.0f   // N(0,0.036)*64 -> N(0,2.3): centered in e2m1 range +-6

typedef __attribute__((ext_vector_type(4)))  float f32x4;
typedef __attribute__((ext_vector_type(4)))  int   int4v;
typedef __attribute__((ext_vector_type(8)))  int   int8v;

// ---- async global->LDS, 16B per lane (wave-uniform base + lane*16) ----
__device__ __forceinline__ void async_copy16(const void* gptr, void* lptr) {
    __builtin_amdgcn_global_load_lds(
        (const __attribute__((address_space(1))) unsigned int*)gptr,
        (__attribute__((address_space(3))) unsigned int*)lptr,
        16, 0, 0);
}

// monotone float->u32 (order-preserving for all finite floats)
__device__ __forceinline__ unsigned mono_u32(float v) {
    unsigned u = __float_as_uint(v);
    return u ^ ((unsigned)(((int)u) >> 31) | 0x80000000u);
}

// max with a DPP row_ror'd copy (16-lane row, pure VALU — no LDS traffic)
template <int CTRL>
__device__ __forceinline__ unsigned row_max_step(unsigned v) {
    unsigned t = (unsigned)__builtin_amdgcn_update_dpp(
        0, (int)v, CTRL, 0xF, 0xF, false);
    return v > t ? v : t;
}

// fp4 e2m1 encode, round-to-nearest: values {0,.5,1,1.5,2,3,4,6} (+sign)
__device__ __forceinline__ unsigned enc_fp4(float v) {
    float a = fabsf(v);
    unsigned c = (unsigned)(a >= 0.25f) + (a >= 0.75f) + (a >= 1.25f) +
                 (a >= 1.75f) + (a >= 2.5f) + (a >= 3.5f) + (a >= 5.0f);
    return c | (v < 0.0f ? 8u : 0u);
}

// fp32 -> bf16 bits, round-to-nearest-even (no NaN inputs here)
__device__ __forceinline__ unsigned f2bf(float f) {
    unsigned u = __float_as_uint(f);
    return (u + (((u >> 16) & 1u) + 0x7fffu)) >> 16;
}
__device__ __forceinline__ float bf_lo(unsigned w) {   // low bf16 of packed pair
    return __uint_as_float(w << 16);
}
__device__ __forceinline__ float bf_hi(unsigned w) {   // high bf16
    return __uint_as_float(w & 0xffff0000u);
}

// fp4 operand: HW reads only v[0:3] of the 8-reg tuple (cbsz/blgp=4).
// High half is compile-time zero — loads are 1x b128, not 2x (R10 fix:
// R7/R8 loaded 32B/fragment; the second 16B was architecturally ignored).
__device__ __forceinline__ int8v to8(int4v q) {
    int8v r;
    r[0] = q[0]; r[1] = q[1]; r[2] = q[2]; r[3] = q[3];
    r[4] = 0; r[5] = 0; r[6] = 0; r[7] = 0;
    return r;
}

// ---------------------------------------------------------------------
// Kernel 1: per-row L2 norm over concat(a,b); write fp4-e2m1 nibbles of
// (x_norm * 64). Optionally also write bf16 normalized rows (xb) for
// the loss gather. Zeroes best[row].
// ---------------------------------------------------------------------
__global__ __launch_bounds__(256) void normalize_kernel(
    const float* __restrict__ a, const float* __restrict__ b,
    unsigned char* __restrict__ xq, float* __restrict__ invn,
    unsigned long long* __restrict__ best,
    unsigned* __restrict__ xb) {           // nullable
    int wave = threadIdx.x >> 6;
    int lane = threadIdx.x & 63;
    int row  = blockIdx.x * 4 + wave;

    const float2* pa = (const float2*)(a + (size_t)row * DHALF);  // 192 pairs
    const float2* pb = (const float2*)(b + (size_t)row * DHALF);

    float2 va[3], vb[3];
    float s = 0.0f;
#pragma unroll
    for (int it = 0; it < 3; ++it) {
        va[it] = pa[lane + 64 * it];
        s += va[it].x * va[it].x + va[it].y * va[it].y;
    }
#pragma unroll
    for (int it = 0; it < 3; ++it) {
        vb[it] = pb[lane + 64 * it];
        s += vb[it].x * vb[it].x + vb[it].y * vb[it].y;
    }
#pragma unroll
    for (int d = 1; d < 64; d <<= 1) s += __shfl_xor(s, d, 64);

    float inv = 1.0f / fmaxf(sqrtf(s), EPSF);
    if (lane == 0) { invn[row] = inv; best[row] = 0ull; }
    float qs = inv * QSCALE;

    unsigned char* px = xq + (size_t)row * ROWB;
#pragma unroll
    for (int it = 0; it < 3; ++it)
        px[lane + 64 * it] =
            (unsigned char)(enc_fp4(va[it].x * qs) | (enc_fp4(va[it].y * qs) << 4));
#pragma unroll
    for (int it = 0; it < 3; ++it)
        px[192 + lane + 64 * it] =
            (unsigned char)(enc_fp4(vb[it].x * qs) | (enc_fp4(vb[it].y * qs) << 4));

    if (xb) {   // uniform branch
        unsigned* pw = xb + (size_t)row * (DFULL / 2);   // 384 packed pairs
#pragma unroll
        for (int it = 0; it < 3; ++it)
            pw[lane + 64 * it] =
                f2bf(va[it].x * inv) | (f2bf(va[it].y * inv) << 16);
#pragma unroll
        for (int it = 0; it < 3; ++it)
            pw[192 + lane + 64 * it] =
                f2bf(vb[it].x * inv) | (f2bf(vb[it].y * inv) << 16);
    }
}

// ---------------------------------------------------------------------
// Kernel 2: scaled dots via MX-fp4 16x16x128 MFMA, 128x128 tile, BK=128
// elems = 64 B/row, upper-triangle blocks (symmetry). Dbuf LDS (R8),
// rolled K-loop (R4), 2-way swizzle (R7), packed-key DPP epilogue (R6).
// R10: one ds_read_b128 per fragment (8/wave/K-step, was 16 — the
// second 16B fed operand regs v[4:7] that fp4 fmt ignores).
// ---------------------------------------------------------------------
__global__ __launch_bounds__(256, 3) void argmax_kernel(
    const unsigned char* __restrict__ xq,
    unsigned long long* __restrict__ best) {
    __shared__ unsigned char As[2][128 * 64];
    __shared__ unsigned char Bs[2][128 * 64];

    // decode upper-triangle pair: k -> (rb <= cb)
    int k = blockIdx.x;
    int i = (int)((sqrtf(8.0f * (float)k + 1.0f) - 1.0f) * 0.5f);
    while ((i + 1) * (i + 2) / 2 <= k) ++i;
    while (i * (i + 1) / 2 > k) --i;
    int cb = i;
    int rb = k - i * (i + 1) / 2;   // rb <= cb
    int r0 = rb * 128, c0 = cb * 128;

    int tid  = threadIdx.x;
    int wave = tid >> 6, lane = tid & 63;
    int wr = wave >> 1, wc = wave & 1;
    int quad = lane >> 4, l15 = lane & 15;

    f32x4 acc[4][4] = {};
    const int SC = 0x7f7f7f7f;      // e8m0 scales = 1.0 in every byte

    // staging pointers: 2 rounds x 256 threads cover 512 granules/tile
    const unsigned char* gA[2];
    const unsigned char* gB[2];
    int lofs[2];
#pragma unroll
    for (int r2 = 0; r2 < 2; ++r2) {
        int idx = r2 * 256 + tid;          // 0..511
        int r   = idx >> 2;                // 0..127
        int s   = idx & 3;                 // dst slot
        int g   = s ^ ((r ^ (r >> 2)) & 3);   // swizzled source granule
        gA[r2] = xq + (size_t)(r0 + r) * ROWB + (g << 4);
        gB[r2] = xq + (size_t)(c0 + r) * ROWB + (g << 4);
        lofs[r2] = idx * 16;
    }

    // fragment LDS offset: lane's 32 k-elems = source granule `quad`
    int s0 = ((quad ^ ((l15 ^ (l15 >> 2)) & 3)) << 4);

    auto stage = [&](int k0b, int buf) {
        async_copy16(gA[0] + k0b, &As[buf][lofs[0]]);
        async_copy16(gA[1] + k0b, &As[buf][lofs[1]]);
        async_copy16(gB[0] + k0b, &Bs[buf][lofs[0]]);
        async_copy16(gB[1] + k0b, &Bs[buf][lofs[1]]);
    };
    auto compute = [&](int buf) {
        const unsigned char* Ab = As[buf];
        const unsigned char* Bb = Bs[buf];
        int8v bfr[4];
#pragma unroll
        for (int t = 0; t < 4; ++t)
            bfr[t] = to8(*(const int4v*)(&Bb[(wc * 64 + t * 16 + l15) * 64 + s0]));
#pragma unroll
        for (int ti = 0; ti < 4; ++ti) {
            int8v a8 = to8(*(const int4v*)(&Ab[(wr * 64 + ti * 16 + l15) * 64 + s0]));
#pragma unroll
            for (int tj = 0; tj < 4; ++tj)
                acc[ti][tj] = __builtin_amdgcn_mfma_scale_f32_16x16x128_f8f6f4(
                    a8, bfr[tj], acc[ti][tj], 4, 4, 0, SC, 0, SC);
        }
    };

    stage(0, 0);
    __syncthreads();
    int buf = 0;
#pragma unroll 1
    for (int k0b = 64; k0b < ROWB; k0b += 64) {   // 5 pipelined steps
        stage(k0b, buf ^ 1);
        compute(buf);
        __syncthreads();
        buf ^= 1;
    }
    compute(buf);                // last tile; epilogue is register-only

    int rbase = r0 + wr * 64, cbase = c0 + wc * 64;

    // Row-direction: packed key = mono(v)&~63 | (tj<<4) | l15; DPP reduce.
#pragma unroll
    for (int ti = 0; ti < 4; ++ti) {
#pragma unroll
        for (int reg = 0; reg < 4; ++reg) {
            int grow = rbase + ti * 16 + quad * 4 + reg;
            unsigned bk = 0;
#pragma unroll
            for (int tj = 0; tj < 4; ++tj) {
                float v   = acc[ti][tj][reg];
                int  gcol = cbase + tj * 16 + l15;
                if (gcol == grow) v = -1.0e30f;   // diagonal mask
                unsigned u = (mono_u32(v) & ~63u) | (unsigned)((tj << 4) | l15);
                bk = bk > u ? bk : u;
            }
            bk = row_max_step<0x121>(bk);   // ror 1
            bk = row_max_step<0x122>(bk);   // ror 2
            bk = row_max_step<0x124>(bk);   // ror 4
            bk = row_max_step<0x128>(bk);   // ror 8
            if (l15 == 0) {
                int col = cbase + (int)(((bk >> 4) & 3u) * 16u + (bk & 15u));
                unsigned long long gk =
                    ((unsigned long long)(bk & ~63u) << 32) | (unsigned)col;
                atomicMax(&best[grow], gk);
            }
        }
    }

    // Column-direction (off-diagonal blocks)
    if (rb != cb) {
#pragma unroll
        for (int tj = 0; tj < 4; ++tj) {
            unsigned bk = 0;
#pragma unroll
            for (int ti = 0; ti < 4; ++ti)
#pragma unroll
                for (int reg = 0; reg < 4; ++reg) {
                    unsigned u = (mono_u32(acc[ti][tj][reg]) & ~63u) |
                                 (unsigned)((ti << 4) | (quad << 2) | reg);
                    bk = bk > u ? bk : u;
                }
            unsigned t16 = (unsigned)__shfl_xor((int)bk, 16, 64);
            bk = bk > t16 ? bk : t16;
            unsigned t32 = (unsigned)__shfl_xor((int)bk, 32, 64);
            bk = bk > t32 ? bk : t32;
            if (quad == 0) {
                int grow = rbase + (int)(((bk >> 4) & 3u) * 16u +
                                         ((bk >> 2) & 3u) * 4u + (bk & 3u));
                int gcol = cbase + tj * 16 + l15;
                unsigned long long gk =
                    ((unsigned long long)(bk & ~63u) << 32) | (unsigned)grow;
                atomicMax(&best[gcol], gk);
            }
        }
    }
}

// ---------------------------------------------------------------------
// Kernel 3a: loss from bf16 normalized rows (50 MB vs 100 MB fp32 path)
// ---------------------------------------------------------------------
__global__ __launch_bounds__(256) void loss_bf16_kernel(
    const unsigned* __restrict__ xb,
    const unsigned long long* __restrict__ best,
    float* __restrict__ terms) {
    int wave = threadIdx.x >> 6;
    int lane = threadIdx.x & 63;
    int row  = blockIdx.x * 4 + wave;

    int j = (int)(best[row] & 0xffffffffull);
    const uint2* pi = (const uint2*)(xb + (size_t)row * (DFULL / 2));
    const uint2* pj = (const uint2*)(xb + (size_t)j   * (DFULL / 2));

    float s = 0.0f;
#pragma unroll
    for (int it = 0; it < 3; ++it) {
        int kk = lane + 64 * it;
        uint2 wi = pi[kk], wj = pj[kk];
        float d0 = bf_lo(wi.x) - bf_lo(wj.x) + EPSF;
        float d1 = bf_hi(wi.x) - bf_hi(wj.x) + EPSF;
        float d2 = bf_lo(wi.y) - bf_lo(wj.y) + EPSF;
        float d3 = bf_hi(wi.y) - bf_hi(wj.y) + EPSF;
        s += d0 * d0 + d1 * d1 + d2 * d2 + d3 * d3;
    }
#pragma unroll
    for (int d = 1; d < 64; d <<= 1) s += __shfl_xor(s, d, 64);

    if (lane == 0) terms[row] = logf(sqrtf(s) + EPSF);
}

// ---------------------------------------------------------------------
// Kernel 3b: fallback — loss from fp32 originals (if ws too small)
// ---------------------------------------------------------------------
__global__ __launch_bounds__(256) void loss_kernel(
    const float* __restrict__ a, const float* __restrict__ b,
    const float* __restrict__ invn,
    const unsigned long long* __restrict__ best,
    float* __restrict__ terms) {
    int wave = threadIdx.x >> 6;
    int lane = threadIdx.x & 63;
    int row  = blockIdx.x * 4 + wave;

    int j = (int)(best[row] & 0xffffffffull);
    float ii = invn[row], ij = invn[j];

    const float2* pai = (const float2*)(a + (size_t)row * DHALF);
    const float2* pbi = (const float2*)(b + (size_t)row * DHALF);
    const float2* paj = (const float2*)(a + (size_t)j * DHALF);
    const float2* pbj = (const float2*)(b + (size_t)j * DHALF);

    float s = 0.0f;
#pragma unroll
    for (int it = 0; it < 3; ++it) {
        int kk = lane + 64 * it;
        float2 di = pai[kk], dj = paj[kk];
        float dx = di.x * ii - dj.x * ij + EPSF;
        float dy = di.y * ii - dj.y * ij + EPSF;
        s += dx * dx + dy * dy;
    }
#pragma unroll
    for (int it = 0; it < 3; ++it) {
        int kk = lane + 64 * it;
        float2 di = pbi[kk], dj = pbj[kk];
        float dx = di.x * ii - dj.x * ij + EPSF;
        float dy = di.y * ii - dj.y * ij + EPSF;
        s += dx * dx + dy * dy;
    }
#pragma unroll
    for (int d = 1; d < 64; d <<= 1) s += __shfl_xor(s, d, 64);

    if (lane == 0) terms[row] = logf(sqrtf(s) + EPSF);
}

// ---------------------------------------------------------------------
// Kernel 4: single-block tree reduction of terms -> out[0] = -mean
// ---------------------------------------------------------------------
__global__ __launch_bounds__(1024) void reduce_kernel(
    const float* __restrict__ terms, float* __restrict__ out) {
    __shared__ float partial[16];
    int tid = threadIdx.x;
    float s = 0.0f;
#pragma unroll
    for (int it = 0; it < NROWS / 1024; ++it) s += terms[tid + 1024 * it];
#pragma unroll
    for (int d = 1; d < 64; d <<= 1) s += __shfl_xor(s, d, 64);
    if ((tid & 63) == 0) partial[tid >> 6] = s;
    __syncthreads();
    if (tid < 16) {
        s = partial[tid];
#pragma unroll
        for (int d = 1; d < 16; d <<= 1) s += __shfl_xor(s, d, 16);
        if (tid == 0) out[0] = -s * (1.0f / (float)NROWS);
    }
}

// ---------------------------------------------------------------------
extern "C" void kernel_launch(void* const* d_in, const int* in_sizes, int n_in,
                              void* d_out, int out_size, void* d_ws, size_t ws_size,
                              hipStream_t stream) {
    const float* a = (const float*)d_in[0];
    const float* b = (const float*)d_in[1];
    float* out = (float*)d_out;

    char* ws = (char*)d_ws;
    unsigned char* xq = (unsigned char*)ws;                                    // 6291456 B
    unsigned long long* best = (unsigned long long*)(ws + 6291456);            // 131072 B
    float* invn  = (float*)(ws + 6291456 + 131072);                            // 65536 B
    float* terms = (float*)(ws + 6291456 + 131072 + 65536);                    // 65536 B
    unsigned* xb = (unsigned*)(ws + 6291456 + 131072 + 65536 + 65536);         // 25165824 B
    const size_t need_xb = 6291456ull + 131072 + 65536 + 65536 + 25165824;
    const bool use_xb = ws_size >= need_xb;   // constant across calls

    const int NTILE = NROWS / 128;                     // 128
    const int NBLK  = NTILE * (NTILE + 1) / 2;         // 8256

    normalize_kernel<<<NROWS / 4, 256, 0, stream>>>(
        a, b, xq, invn, best, use_xb ? xb : (unsigned*)nullptr);
    argmax_kernel<<<NBLK, 256, 0, stream>>>(xq, best);
    if (use_xb)
        loss_bf16_kernel<<<NROWS / 4, 256, 0, stream>>>(xb, best, terms);
    else
        loss_kernel<<<NROWS / 4, 256, 0, stream>>>(a, b, invn, best, terms);
    reduce_kernel<<<1, 1024, 0, stream>>>(terms, out);
}